// Round 1
// baseline (12726.713 us; speedup 1.0000x reference)
//
#include <hip/hip_runtime.h>
#include <cstdio>
#include <cstdint>

// R15: kill the float atomics. R14's k_message spent 2x5.4ms doing 102.4M
// device-scope fp32 atomicAdds (WRITE_SIZE = 102.4M x 32B = 3.28GB, VALUBusy
// 2.8% -> pure atomic stall at ~19G atomics/s). Replace scatter-atomics with a
// per-call dst-CSR build (int histogram + block-scan + fill: 6.4M int atomics
// total) and a fused gather+message+update kernel, one thread per node,
// register accumulation, ping-pong h buffers. Algebra: message layer-2 is
// linear -> hoist W2 out of the edge loop (sum relu first); h[dst] layer-1
// contribution hoisted out of the edge loop too. Fallback to the R14 atomic
// path if workspace is too small for the CSR (needs ~52MB).

__attribute__((constructor)) static void atomgnn_r15_load_beacon() {
    fprintf(stderr, "ATOMGNN_R15_SOURCE_LOADED\n");
    fflush(stderr);
}

#define NN_REF 100000
#define NE_REF 3200000

// zero a float/int buffer (4B words), grid-stride
__global__ void __launch_bounds__(256)
k_zero(float* __restrict__ p, int n)
{
    int i = blockIdx.x * 256 + threadIdx.x;
    int stride = gridDim.x * 256;
    for (; i < n; i += stride) p[i] = 0.0f;
}

// encoder: h = relu(nf @ w1 + b1) @ w2 + b2   (16 -> 32 -> 32)
__global__ void __launch_bounds__(256)
k_encode(const float* __restrict__ nf,
         const float* __restrict__ w1g, const float* __restrict__ b1g,
         const float* __restrict__ w2g, const float* __restrict__ b2g,
         float* __restrict__ h, int n_nodes)
{
    __shared__ float sw1[16 * 32];
    __shared__ float sw2[32 * 32];
    __shared__ float sb1[32];
    __shared__ float sb2[32];
    for (int i = threadIdx.x; i < 16 * 32; i += 256) sw1[i] = w1g[i];
    for (int i = threadIdx.x; i < 32 * 32; i += 256) sw2[i] = w2g[i];
    if (threadIdx.x < 32) {
        sb1[threadIdx.x] = b1g[threadIdx.x];
        sb2[threadIdx.x] = b2g[threadIdx.x];
    }
    __syncthreads();
    int n = blockIdx.x * 256 + threadIdx.x;
    if (n >= n_nodes) return;

    const float4* p = (const float4*)(nf + (size_t)n * 16);
    float x[16];
    #pragma unroll
    for (int c = 0; c < 4; c++) {
        float4 v = p[c];
        x[4 * c] = v.x; x[4 * c + 1] = v.y; x[4 * c + 2] = v.z; x[4 * c + 3] = v.w;
    }

    float acc[32];
    #pragma unroll
    for (int j = 0; j < 32; j++) acc[j] = sb1[j];
    #pragma unroll 4
    for (int k = 0; k < 16; k++) {
        float xk = x[k];
        const float* wr = &sw1[k * 32];
        #pragma unroll
        for (int j = 0; j < 32; j++) acc[j] = fmaf(xk, wr[j], acc[j]);
    }
    #pragma unroll
    for (int j = 0; j < 32; j++) acc[j] = fmaxf(acc[j], 0.0f);

    float o[32];
    #pragma unroll
    for (int j = 0; j < 32; j++) o[j] = sb2[j];
    #pragma unroll 4
    for (int k = 0; k < 32; k++) {
        float hk = acc[k];
        const float* wr = &sw2[k * 32];
        #pragma unroll
        for (int j = 0; j < 32; j++) o[j] = fmaf(hk, wr[j], o[j]);
    }
    float4* hp = (float4*)(h + (size_t)n * 32);
    #pragma unroll
    for (int c = 0; c < 8; c++)
        hp[c] = make_float4(o[4 * c], o[4 * c + 1], o[4 * c + 2], o[4 * c + 3]);
}

// -------- CSR build: histogram -> exclusive scan -> fill --------

__global__ void __launch_bounds__(256)
k_hist(const int2* __restrict__ edges, int* __restrict__ cnt, int n_edges)
{
    int e = blockIdx.x * 256 + threadIdx.x;
    if (e >= n_edges) return;
    atomicAdd(&cnt[edges[e].y], 1);
}

// per-block inclusive scan of cnt -> rs holds block-local EXCLUSIVE scan,
// bsum[b] holds block total
__global__ void __launch_bounds__(256)
k_scan_block(const int* __restrict__ cnt, int* __restrict__ rs,
             int* __restrict__ bsum, int n)
{
    __shared__ int sd[256];
    int t = threadIdx.x;
    int i = blockIdx.x * 256 + t;
    int v = (i < n) ? cnt[i] : 0;
    sd[t] = v;
    __syncthreads();
    int val = v;
    for (int off = 1; off < 256; off <<= 1) {
        int add = (t >= off) ? sd[t - off] : 0;
        __syncthreads();
        val += add;
        sd[t] = val;
        __syncthreads();
    }
    if (i < n) rs[i] = val - v;           // exclusive within block
    if (t == 255) bsum[blockIdx.x] = val; // block total
}

// single-block scan of block totals -> bsum becomes exclusive prefix of blocks.
// thread 0 also writes rs[n_nodes] = n_edges (total).
__global__ void __launch_bounds__(1024)
k_scan_bsum(int* __restrict__ bsum, int nb, int* __restrict__ rs,
            int n_nodes, int n_edges)
{
    __shared__ int sd[1024];
    int t = threadIdx.x;
    int v = (t < nb) ? bsum[t] : 0;
    sd[t] = v;
    __syncthreads();
    int val = v;
    for (int off = 1; off < 1024; off <<= 1) {
        int add = (t >= off) ? sd[t - off] : 0;
        __syncthreads();
        val += add;
        sd[t] = val;
        __syncthreads();
    }
    if (t < nb) bsum[t] = val - v;  // exclusive prefix of block totals
    if (t == 0) rs[n_nodes] = n_edges;
}

// add block offsets -> rs is global exclusive scan; also seed cursor = rs
__global__ void __launch_bounds__(256)
k_scan_add(int* __restrict__ rs, int* __restrict__ cursor,
           const int* __restrict__ bsum, int n)
{
    int i = blockIdx.x * 256 + threadIdx.x;
    if (i < n) {
        int v = rs[i] + bsum[blockIdx.x];
        rs[i] = v;
        cursor[i] = v;
    }
}

// scatter edges into dst-sorted slots: slot = (src, edge_idx)
__global__ void __launch_bounds__(256)
k_fill(const int2* __restrict__ edges, int* __restrict__ cursor,
       int2* __restrict__ slots, int n_edges)
{
    int e = blockIdx.x * 256 + threadIdx.x;
    if (e >= n_edges) return;
    int2 ed = edges[e];
    int pos = atomicAdd(&cursor[ed.y], 1);
    slots[pos] = make_int2(ed.x, e);
}

// -------- fused round: gather + message MLP + update MLP, ping-pong h --------
// per node n:
//   base   = msg_b1 + h[n] @ msg_w1[32:64]          (dst half hoisted)
//   rsum   = sum_{e: dst=n} relu(base + h[src]@W1[0:32] + ef@W1[64:68])
//   agg    = rsum @ msg_w2 + deg * msg_b2           (W2 hoisted: linearity)
//   h_out  = h[n] + relu([h[n],agg] @ upd_w1 + ub1) @ upd_w2 + ub2
__global__ void __launch_bounds__(256)
k_round(const float* __restrict__ h_in, float* __restrict__ h_out,
        const int* __restrict__ row_start, const int2* __restrict__ slots,
        const float4* __restrict__ ef,
        const float* __restrict__ mw1, const float* __restrict__ mb1,
        const float* __restrict__ mw2, const float* __restrict__ mb2,
        const float* __restrict__ uw1, const float* __restrict__ ub1,
        const float* __restrict__ uw2, const float* __restrict__ ub2,
        int n_nodes)
{
    __shared__ float smw1[68 * 32];
    __shared__ float smw2[32 * 32];
    __shared__ float suw1[64 * 32];
    __shared__ float suw2[32 * 32];
    __shared__ float smb1[32], smb2[32], sub1[32], sub2[32];
    for (int i = threadIdx.x; i < 68 * 32; i += 256) smw1[i] = mw1[i];
    for (int i = threadIdx.x; i < 32 * 32; i += 256) smw2[i] = mw2[i];
    for (int i = threadIdx.x; i < 64 * 32; i += 256) suw1[i] = uw1[i];
    for (int i = threadIdx.x; i < 32 * 32; i += 256) suw2[i] = uw2[i];
    if (threadIdx.x < 32) {
        smb1[threadIdx.x] = mb1[threadIdx.x];
        smb2[threadIdx.x] = mb2[threadIdx.x];
        sub1[threadIdx.x] = ub1[threadIdx.x];
        sub2[threadIdx.x] = ub2[threadIdx.x];
    }
    __syncthreads();
    int n = blockIdx.x * 256 + threadIdx.x;
    if (n >= n_nodes) return;

    // base = msg_b1 + h[n] @ mw1[rows 32..63]
    float base[32];
    {
        const float4* hp = (const float4*)(h_in + (size_t)n * 32);
        #pragma unroll
        for (int j = 0; j < 32; j++) base[j] = smb1[j];
        #pragma unroll
        for (int c = 0; c < 8; c++) {
            float4 xv = hp[c];
            float xs[4] = {xv.x, xv.y, xv.z, xv.w};
            #pragma unroll
            for (int kk = 0; kk < 4; kk++) {
                float xk = xs[kk];
                const float* wr = &smw1[(32 + c * 4 + kk) * 32];
                #pragma unroll
                for (int j = 0; j < 32; j++) base[j] = fmaf(xk, wr[j], base[j]);
            }
        }
    }

    float rsum[32];
    #pragma unroll
    for (int j = 0; j < 32; j++) rsum[j] = 0.0f;

    int s0 = row_start[n];
    int s1 = row_start[n + 1];
    for (int s = s0; s < s1; s++) {
        int2 sl = slots[s];
        const float4* hs = (const float4*)(h_in + (size_t)sl.x * 32);
        float4 ev = ef[sl.y];
        float acc[32];
        #pragma unroll
        for (int j = 0; j < 32; j++) acc[j] = base[j];
        #pragma unroll
        for (int c = 0; c < 8; c++) {
            float4 xv = hs[c];
            float xs[4] = {xv.x, xv.y, xv.z, xv.w};
            #pragma unroll
            for (int kk = 0; kk < 4; kk++) {
                float xk = xs[kk];
                const float* wr = &smw1[(c * 4 + kk) * 32];
                #pragma unroll
                for (int j = 0; j < 32; j++) acc[j] = fmaf(xk, wr[j], acc[j]);
            }
        }
        {
            float exs[4] = {ev.x, ev.y, ev.z, ev.w};
            #pragma unroll
            for (int kk = 0; kk < 4; kk++) {
                float xk = exs[kk];
                const float* wr = &smw1[(64 + kk) * 32];
                #pragma unroll
                for (int j = 0; j < 32; j++) acc[j] = fmaf(xk, wr[j], acc[j]);
            }
        }
        #pragma unroll
        for (int j = 0; j < 32; j++) rsum[j] += fmaxf(acc[j], 0.0f);
    }

    // agg = rsum @ mw2 + deg * mb2  (deg=0 -> agg=0, matches empty segment_sum)
    float deg = (float)(s1 - s0);
    float agg[32];
    #pragma unroll
    for (int j = 0; j < 32; j++) agg[j] = deg * smb2[j];
    #pragma unroll 4
    for (int k = 0; k < 32; k++) {
        float rk = rsum[k];
        const float* wr = &smw2[k * 32];
        #pragma unroll
        for (int j = 0; j < 32; j++) agg[j] = fmaf(rk, wr[j], agg[j]);
    }

    // update MLP
    float hv[32];
    {
        const float4* hp = (const float4*)(h_in + (size_t)n * 32);
        #pragma unroll
        for (int c = 0; c < 8; c++) {
            float4 xv = hp[c];
            hv[4 * c] = xv.x; hv[4 * c + 1] = xv.y;
            hv[4 * c + 2] = xv.z; hv[4 * c + 3] = xv.w;
        }
    }
    float acc2[32];
    #pragma unroll
    for (int j = 0; j < 32; j++) acc2[j] = sub1[j];
    #pragma unroll 4
    for (int k = 0; k < 32; k++) {
        float xk = hv[k];
        const float* wr = &suw1[k * 32];
        #pragma unroll
        for (int j = 0; j < 32; j++) acc2[j] = fmaf(xk, wr[j], acc2[j]);
    }
    #pragma unroll 4
    for (int k = 0; k < 32; k++) {
        float xk = agg[k];
        const float* wr = &suw1[(32 + k) * 32];
        #pragma unroll
        for (int j = 0; j < 32; j++) acc2[j] = fmaf(xk, wr[j], acc2[j]);
    }
    float o[32];
    #pragma unroll
    for (int j = 0; j < 32; j++) o[j] = sub2[j];
    #pragma unroll 4
    for (int k = 0; k < 32; k++) {
        float xk = fmaxf(acc2[k], 0.0f);
        const float* wr = &suw2[k * 32];
        #pragma unroll
        for (int j = 0; j < 32; j++) o[j] = fmaf(xk, wr[j], o[j]);
    }
    float4* op = (float4*)(h_out + (size_t)n * 32);
    #pragma unroll
    for (int c = 0; c < 8; c++)
        op[c] = make_float4(hv[4 * c] + o[4 * c], hv[4 * c + 1] + o[4 * c + 1],
                            hv[4 * c + 2] + o[4 * c + 2], hv[4 * c + 3] + o[4 * c + 3]);
}

// -------- R14 fallback kernels (atomic path), used only if ws too small -----

__global__ void __launch_bounds__(256)
k_message(const float* __restrict__ h, const int2* __restrict__ edges,
          const float4* __restrict__ ef,
          const float* __restrict__ w1g, const float* __restrict__ b1g,
          const float* __restrict__ w2g, const float* __restrict__ b2g,
          float* __restrict__ agg, int n_edges)
{
    __shared__ float sw1[68 * 32];
    __shared__ float sw2[32 * 32];
    __shared__ float sb1[32];
    __shared__ float sb2[32];
    for (int i = threadIdx.x; i < 68 * 32; i += 256) sw1[i] = w1g[i];
    for (int i = threadIdx.x; i < 32 * 32; i += 256) sw2[i] = w2g[i];
    if (threadIdx.x < 32) {
        sb1[threadIdx.x] = b1g[threadIdx.x];
        sb2[threadIdx.x] = b2g[threadIdx.x];
    }
    __syncthreads();
    int e = blockIdx.x * 256 + threadIdx.x;
    if (e >= n_edges) return;

    int2 ed = edges[e];
    const float4* hs = (const float4*)(h + (size_t)ed.x * 32);
    const float4* hd = (const float4*)(h + (size_t)ed.y * 32);

    float acc[32];
    #pragma unroll
    for (int j = 0; j < 32; j++) acc[j] = sb1[j];
    #pragma unroll 2
    for (int c = 0; c < 8; c++) {
        float4 xv = hs[c];
        float xs[4] = {xv.x, xv.y, xv.z, xv.w};
        #pragma unroll
        for (int kk = 0; kk < 4; kk++) {
            float xk = xs[kk];
            const float* wr = &sw1[(c * 4 + kk) * 32];
            #pragma unroll
            for (int j = 0; j < 32; j++) acc[j] = fmaf(xk, wr[j], acc[j]);
        }
    }
    #pragma unroll 2
    for (int c = 0; c < 8; c++) {
        float4 xv = hd[c];
        float xs[4] = {xv.x, xv.y, xv.z, xv.w};
        #pragma unroll
        for (int kk = 0; kk < 4; kk++) {
            float xk = xs[kk];
            const float* wr = &sw1[(32 + c * 4 + kk) * 32];
            #pragma unroll
            for (int j = 0; j < 32; j++) acc[j] = fmaf(xk, wr[j], acc[j]);
        }
    }
    {
        float4 evv = ef[e];
        float ex[4] = {evv.x, evv.y, evv.z, evv.w};
        #pragma unroll
        for (int kk = 0; kk < 4; kk++) {
            float xk = ex[kk];
            const float* wr = &sw1[(64 + kk) * 32];
            #pragma unroll
            for (int j = 0; j < 32; j++) acc[j] = fmaf(xk, wr[j], acc[j]);
        }
    }
    #pragma unroll
    for (int j = 0; j < 32; j++) acc[j] = fmaxf(acc[j], 0.0f);

    float o[32];
    #pragma unroll
    for (int j = 0; j < 32; j++) o[j] = sb2[j];
    #pragma unroll 4
    for (int k = 0; k < 32; k++) {
        float hk = acc[k];
        const float* wr = &sw2[k * 32];
        #pragma unroll
        for (int j = 0; j < 32; j++) o[j] = fmaf(hk, wr[j], o[j]);
    }
    float* ap = agg + (size_t)ed.y * 32;
    #pragma unroll
    for (int j = 0; j < 32; j++) atomicAdd(ap + j, o[j]);
}

__global__ void __launch_bounds__(256)
k_update(float* h, const float* __restrict__ agg,
         const float* __restrict__ w1g, const float* __restrict__ b1g,
         const float* __restrict__ w2g, const float* __restrict__ b2g,
         int n_nodes)
{
    __shared__ float sw1[64 * 32];
    __shared__ float sw2[32 * 32];
    __shared__ float sb1[32];
    __shared__ float sb2[32];
    for (int i = threadIdx.x; i < 64 * 32; i += 256) sw1[i] = w1g[i];
    for (int i = threadIdx.x; i < 32 * 32; i += 256) sw2[i] = w2g[i];
    if (threadIdx.x < 32) {
        sb1[threadIdx.x] = b1g[threadIdx.x];
        sb2[threadIdx.x] = b2g[threadIdx.x];
    }
    __syncthreads();
    int n = blockIdx.x * 256 + threadIdx.x;
    if (n >= n_nodes) return;

    const float4* hp = (const float4*)(h + (size_t)n * 32);
    const float4* ap = (const float4*)(agg + (size_t)n * 32);

    float hv[32];
    float acc[32];
    #pragma unroll
    for (int j = 0; j < 32; j++) acc[j] = sb1[j];
    #pragma unroll 2
    for (int c = 0; c < 8; c++) {
        float4 xv = hp[c];
        hv[4 * c] = xv.x; hv[4 * c + 1] = xv.y; hv[4 * c + 2] = xv.z; hv[4 * c + 3] = xv.w;
        float xs[4] = {xv.x, xv.y, xv.z, xv.w};
        #pragma unroll
        for (int kk = 0; kk < 4; kk++) {
            float xk = xs[kk];
            const float* wr = &sw1[(c * 4 + kk) * 32];
            #pragma unroll
            for (int j = 0; j < 32; j++) acc[j] = fmaf(xk, wr[j], acc[j]);
        }
    }
    #pragma unroll 2
    for (int c = 0; c < 8; c++) {
        float4 xv = ap[c];
        float xs[4] = {xv.x, xv.y, xv.z, xv.w};
        #pragma unroll
        for (int kk = 0; kk < 4; kk++) {
            float xk = xs[kk];
            const float* wr = &sw1[(32 + c * 4 + kk) * 32];
            #pragma unroll
            for (int j = 0; j < 32; j++) acc[j] = fmaf(xk, wr[j], acc[j]);
        }
    }
    #pragma unroll
    for (int j = 0; j < 32; j++) acc[j] = fmaxf(acc[j], 0.0f);

    float o[32];
    #pragma unroll
    for (int j = 0; j < 32; j++) o[j] = sb2[j];
    #pragma unroll 4
    for (int k = 0; k < 32; k++) {
        float hk = acc[k];
        const float* wr = &sw2[k * 32];
        #pragma unroll
        for (int j = 0; j < 32; j++) o[j] = fmaf(hk, wr[j], o[j]);
    }
    float4* op = (float4*)(h + (size_t)n * 32);
    #pragma unroll
    for (int c = 0; c < 8; c++)
        op[c] = make_float4(hv[4 * c] + o[4 * c], hv[4 * c + 1] + o[4 * c + 1],
                            hv[4 * c + 2] + o[4 * c + 2], hv[4 * c + 3] + o[4 * c + 3]);
}

// head: out = (relu(h @ w1 + b1) @ w2 + b2)[:, 0]   (fp32 out)
__global__ void AtomGNN_56169582297457_kernel(const float* h, const float* w1g, const float* b1g, const float* w2g, const float* b2g, float* out, int n_nodes) {
    __shared__ float sw1[32 * 32];
    __shared__ float sb1[32];
    __shared__ float sw2[32];
    __shared__ float sb2;
    for (int i = threadIdx.x; i < 32 * 32; i += 256) sw1[i] = w1g[i];
    if (threadIdx.x < 32) {
        sb1[threadIdx.x] = b1g[threadIdx.x];
        sw2[threadIdx.x] = w2g[threadIdx.x];
    }
    if (threadIdx.x == 0) sb2 = b2g[0];
    __syncthreads();
    int n = blockIdx.x * 256 + threadIdx.x;
    if (n >= n_nodes) return;

    const float4* hp = (const float4*)(h + (size_t)n * 32);
    float x[32];
    #pragma unroll
    for (int c = 0; c < 8; c++) {
        float4 xv = hp[c];
        x[4 * c] = xv.x; x[4 * c + 1] = xv.y; x[4 * c + 2] = xv.z; x[4 * c + 3] = xv.w;
    }
    float acc[32];
    #pragma unroll
    for (int j = 0; j < 32; j++) acc[j] = sb1[j];
    #pragma unroll 4
    for (int k = 0; k < 32; k++) {
        float xk = x[k];
        const float* wr = &sw1[k * 32];
        #pragma unroll
        for (int j = 0; j < 32; j++) acc[j] = fmaf(xk, wr[j], acc[j]);
    }
    float val = sb2;
    #pragma unroll
    for (int k = 0; k < 32; k++) val = fmaf(fmaxf(acc[k], 0.0f), sw2[k], val);
    out[n] = val;
}

extern "C" void kernel_launch(void* const* d_in, const int* in_sizes, int n_in,
                              void* d_out, int out_size, void* d_ws, size_t ws_size,
                              hipStream_t stream) {
    const float* nf      = (const float*)d_in[0];
    const int2*  edges   = (const int2*)d_in[1];
    const float4* ef     = (const float4*)d_in[2];
    const float* enc_w1  = (const float*)d_in[3];
    const float* enc_b1  = (const float*)d_in[4];
    const float* enc_w2  = (const float*)d_in[5];
    const float* enc_b2  = (const float*)d_in[6];
    const float* msg_w1  = (const float*)d_in[7];
    const float* msg_b1  = (const float*)d_in[8];
    const float* msg_w2  = (const float*)d_in[9];
    const float* msg_b2  = (const float*)d_in[10];
    const float* upd_w1  = (const float*)d_in[11];
    const float* upd_b1  = (const float*)d_in[12];
    const float* upd_w2  = (const float*)d_in[13];
    const float* upd_b2  = (const float*)d_in[14];
    const float* head_w1 = (const float*)d_in[15];
    const float* head_b1 = (const float*)d_in[16];
    const float* head_w2 = (const float*)d_in[17];
    const float* head_b2 = (const float*)d_in[18];

    int n_nodes = (out_size > 0) ? out_size : NN_REF;
    int n_edges = (in_sizes && n_in > 2 && in_sizes[2] > 0) ? in_sizes[2] / 4 : NE_REF;

    int nb_nodes = (n_nodes + 255) / 256;
    int nb_edges = (n_edges + 255) / 256;

    // CSR workspace layout:
    //   h0[n*32] f32 | h1[n*32] f32 | row_start[n+1] i32 | cursor[n] i32 |
    //   bsum[nb] i32 | pad | slots[E] int2
    float* h0 = (float*)d_ws;
    float* h1 = h0 + (size_t)n_nodes * 32;
    int* row_start = (int*)(h1 + (size_t)n_nodes * 32);
    int* cursor = row_start + (n_nodes + 1);
    int* bsum = cursor + n_nodes;
    uintptr_t slots_addr = ((uintptr_t)(bsum + nb_nodes) + 15) & ~(uintptr_t)15;
    int2* slots = (int2*)slots_addr;
    size_t required = (slots_addr - (uintptr_t)d_ws) + (size_t)n_edges * sizeof(int2);

    bool csr_ok = (nb_nodes <= 1024) &&
                  (ws_size == 0 || ws_size >= required);

    if (csr_ok) {
        k_encode<<<nb_nodes, 256, 0, stream>>>(nf, enc_w1, enc_b1, enc_w2, enc_b2, h0, n_nodes);

        // build dst-CSR once (edges are identical across rounds)
        k_zero<<<256, 256, 0, stream>>>((float*)cursor, n_nodes);      // cursor as cnt
        k_hist<<<nb_edges, 256, 0, stream>>>(edges, cursor, n_edges);
        k_scan_block<<<nb_nodes, 256, 0, stream>>>(cursor, row_start, bsum, n_nodes);
        k_scan_bsum<<<1, 1024, 0, stream>>>(bsum, nb_nodes, row_start, n_nodes, n_edges);
        k_scan_add<<<nb_nodes, 256, 0, stream>>>(row_start, cursor, bsum, n_nodes);
        k_fill<<<nb_edges, 256, 0, stream>>>(edges, cursor, slots, n_edges);

        // ping-pong rounds: h0 -> h1 -> h0
        for (int r = 0; r < 2; r++) {
            const float* hin = (r == 0) ? h0 : h1;
            float* hout      = (r == 0) ? h1 : h0;
            k_round<<<nb_nodes, 256, 0, stream>>>(
                hin, hout, row_start, slots, ef,
                msg_w1 + (size_t)r * 68 * 32, msg_b1 + (size_t)r * 32,
                msg_w2 + (size_t)r * 32 * 32, msg_b2 + (size_t)r * 32,
                upd_w1 + (size_t)r * 64 * 32, upd_b1 + (size_t)r * 32,
                upd_w2 + (size_t)r * 32 * 32, upd_b2 + (size_t)r * 32,
                n_nodes);
        }

        AtomGNN_56169582297457_kernel<<<nb_nodes, 256, 0, stream>>>(
            h0, head_w1, head_b1, head_w2, head_b2, (float*)d_out, n_nodes);
    } else {
        // R14 fallback: atomic scatter path (proven correct, slow)
        float* h   = (float*)d_ws;
        float* agg = h + (size_t)n_nodes * 32;

        k_encode<<<nb_nodes, 256, 0, stream>>>(nf, enc_w1, enc_b1, enc_w2, enc_b2, h, n_nodes);
        for (int r = 0; r < 2; r++) {
            k_zero<<<1024, 256, 0, stream>>>(agg, n_nodes * 32);
            k_message<<<nb_edges, 256, 0, stream>>>(
                h, edges, ef,
                msg_w1 + (size_t)r * 68 * 32, msg_b1 + (size_t)r * 32,
                msg_w2 + (size_t)r * 32 * 32, msg_b2 + (size_t)r * 32,
                agg, n_edges);
            k_update<<<nb_nodes, 256, 0, stream>>>(
                h, agg,
                upd_w1 + (size_t)r * 64 * 32, upd_b1 + (size_t)r * 32,
                upd_w2 + (size_t)r * 32 * 32, upd_b2 + (size_t)r * 32,
                n_nodes);
        }
        AtomGNN_56169582297457_kernel<<<nb_nodes, 256, 0, stream>>>(
            h, head_w1, head_b1, head_w2, head_b2, (float*)d_out, n_nodes);
    }
}

// Round 2
// 3207.602 us; speedup vs baseline: 3.9677x; 3.9677x over previous
//
#include <hip/hip_runtime.h>
#include <cstdio>
#include <cstdint>

// R16: fix k_round's latency-bound collapse (R15: VGPR=256 -> 8% occupancy,
// 391 blocks, serial 32-edge loop of random 128B gathers, VALUBusy 2.9%,
// FETCH 8.2GB). New k_round_wave: one WAVE per dst node, lane = output
// column. h[src] rows are read with wave-uniform addresses (hardware
// broadcast, 1 line per edge instead of 64), per-lane state is scalar,
// W1a column lives in 36 registers, cold-phase weights in LDS, cross-column
// broadcasts via __shfl(.,k,32). Grid-stride 2048 blocks for TLP. Keeps
// R15's CSR build (proven) + W2-hoist + dst-hoist algebra. R14 atomic path
// remains as fallback if workspace is too small.

__attribute__((constructor)) static void atomgnn_r16_load_beacon() {
    fprintf(stderr, "ATOMGNN_R16_SOURCE_LOADED\n");
    fflush(stderr);
}

#define NN_REF 100000
#define NE_REF 3200000

// zero a float/int buffer (4B words), grid-stride
__global__ void __launch_bounds__(256)
k_zero(float* __restrict__ p, int n)
{
    int i = blockIdx.x * 256 + threadIdx.x;
    int stride = gridDim.x * 256;
    for (; i < n; i += stride) p[i] = 0.0f;
}

// encoder: h = relu(nf @ w1 + b1) @ w2 + b2   (16 -> 32 -> 32)
__global__ void __launch_bounds__(256)
k_encode(const float* __restrict__ nf,
         const float* __restrict__ w1g, const float* __restrict__ b1g,
         const float* __restrict__ w2g, const float* __restrict__ b2g,
         float* __restrict__ h, int n_nodes)
{
    __shared__ float sw1[16 * 32];
    __shared__ float sw2[32 * 32];
    __shared__ float sb1[32];
    __shared__ float sb2[32];
    for (int i = threadIdx.x; i < 16 * 32; i += 256) sw1[i] = w1g[i];
    for (int i = threadIdx.x; i < 32 * 32; i += 256) sw2[i] = w2g[i];
    if (threadIdx.x < 32) {
        sb1[threadIdx.x] = b1g[threadIdx.x];
        sb2[threadIdx.x] = b2g[threadIdx.x];
    }
    __syncthreads();
    int n = blockIdx.x * 256 + threadIdx.x;
    if (n >= n_nodes) return;

    const float4* p = (const float4*)(nf + (size_t)n * 16);
    float x[16];
    #pragma unroll
    for (int c = 0; c < 4; c++) {
        float4 v = p[c];
        x[4 * c] = v.x; x[4 * c + 1] = v.y; x[4 * c + 2] = v.z; x[4 * c + 3] = v.w;
    }

    float acc[32];
    #pragma unroll
    for (int j = 0; j < 32; j++) acc[j] = sb1[j];
    #pragma unroll 4
    for (int k = 0; k < 16; k++) {
        float xk = x[k];
        const float* wr = &sw1[k * 32];
        #pragma unroll
        for (int j = 0; j < 32; j++) acc[j] = fmaf(xk, wr[j], acc[j]);
    }
    #pragma unroll
    for (int j = 0; j < 32; j++) acc[j] = fmaxf(acc[j], 0.0f);

    float o[32];
    #pragma unroll
    for (int j = 0; j < 32; j++) o[j] = sb2[j];
    #pragma unroll 4
    for (int k = 0; k < 32; k++) {
        float hk = acc[k];
        const float* wr = &sw2[k * 32];
        #pragma unroll
        for (int j = 0; j < 32; j++) o[j] = fmaf(hk, wr[j], o[j]);
    }
    float4* hp = (float4*)(h + (size_t)n * 32);
    #pragma unroll
    for (int c = 0; c < 8; c++)
        hp[c] = make_float4(o[4 * c], o[4 * c + 1], o[4 * c + 2], o[4 * c + 3]);
}

// -------- CSR build: histogram -> exclusive scan -> fill --------

__global__ void __launch_bounds__(256)
k_hist(const int2* __restrict__ edges, int* __restrict__ cnt, int n_edges)
{
    int e = blockIdx.x * 256 + threadIdx.x;
    if (e >= n_edges) return;
    atomicAdd(&cnt[edges[e].y], 1);
}

__global__ void __launch_bounds__(256)
k_scan_block(const int* __restrict__ cnt, int* __restrict__ rs,
             int* __restrict__ bsum, int n)
{
    __shared__ int sd[256];
    int t = threadIdx.x;
    int i = blockIdx.x * 256 + t;
    int v = (i < n) ? cnt[i] : 0;
    sd[t] = v;
    __syncthreads();
    int val = v;
    for (int off = 1; off < 256; off <<= 1) {
        int add = (t >= off) ? sd[t - off] : 0;
        __syncthreads();
        val += add;
        sd[t] = val;
        __syncthreads();
    }
    if (i < n) rs[i] = val - v;           // exclusive within block
    if (t == 255) bsum[blockIdx.x] = val; // block total
}

__global__ void __launch_bounds__(1024)
k_scan_bsum(int* __restrict__ bsum, int nb, int* __restrict__ rs,
            int n_nodes, int n_edges)
{
    __shared__ int sd[1024];
    int t = threadIdx.x;
    int v = (t < nb) ? bsum[t] : 0;
    sd[t] = v;
    __syncthreads();
    int val = v;
    for (int off = 1; off < 1024; off <<= 1) {
        int add = (t >= off) ? sd[t - off] : 0;
        __syncthreads();
        val += add;
        sd[t] = val;
        __syncthreads();
    }
    if (t < nb) bsum[t] = val - v;  // exclusive prefix of block totals
    if (t == 0) rs[n_nodes] = n_edges;
}

__global__ void __launch_bounds__(256)
k_scan_add(int* __restrict__ rs, int* __restrict__ cursor,
           const int* __restrict__ bsum, int n)
{
    int i = blockIdx.x * 256 + threadIdx.x;
    if (i < n) {
        int v = rs[i] + bsum[blockIdx.x];
        rs[i] = v;
        cursor[i] = v;
    }
}

__global__ void __launch_bounds__(256)
k_fill(const int2* __restrict__ edges, int* __restrict__ cursor,
       int2* __restrict__ slots, int n_edges)
{
    int e = blockIdx.x * 256 + threadIdx.x;
    if (e >= n_edges) return;
    int2 ed = edges[e];
    int pos = atomicAdd(&cursor[ed.y], 1);
    slots[pos] = make_int2(ed.x, e);
}

// -------- fused round, wave-per-node, column-per-lane --------
// wave handles node n; lane c = lane&31 owns column c; halves process two
// edges concurrently.
//   base[c] = mb1[c] + sum_k h[n][k]*W1b[k][c]              (dst hoisted)
//   rsum[c] = sum_edges relu(base[c] + sum_k h[src][k]*W1a[k][c]
//                                    + sum_k ef[k]*W1c[k][c])
//   agg[c]  = deg*mb2[c] + sum_k rsum[k]*W2[k][c]           (W2 hoisted)
//   t[c]    = relu(ub1[c] + sum_k h[n][k]*U1[k][c] + sum_k agg[k]*U1[32+k][c])
//   h_out[n][c] = h[n][c] + ub2[c] + sum_k t[k]*U2[k][c]
__global__ void __launch_bounds__(256)
k_round_wave(const float* __restrict__ h_in, float* __restrict__ h_out,
        const int* __restrict__ row_start, const int2* __restrict__ slots,
        const float4* __restrict__ ef,
        const float* __restrict__ mw1, const float* __restrict__ mb1,
        const float* __restrict__ mw2, const float* __restrict__ mb2,
        const float* __restrict__ uw1, const float* __restrict__ ub1,
        const float* __restrict__ uw2, const float* __restrict__ ub2,
        int n_nodes)
{
    __shared__ float sW1b[32 * 32];   // msg_w1 rows 32..63 (dst half)
    __shared__ float sW2[32 * 32];
    __shared__ float sU1[64 * 32];
    __shared__ float sU2[32 * 32];
    __shared__ float sB[4 * 32];      // mb1 | mb2 | ub1 | ub2
    for (int i = threadIdx.x; i < 32 * 32; i += 256) sW1b[i] = mw1[32 * 32 + i];
    for (int i = threadIdx.x; i < 32 * 32; i += 256) sW2[i]  = mw2[i];
    for (int i = threadIdx.x; i < 64 * 32; i += 256) sU1[i]  = uw1[i];
    for (int i = threadIdx.x; i < 32 * 32; i += 256) sU2[i]  = uw2[i];
    if (threadIdx.x < 32) {
        sB[threadIdx.x]      = mb1[threadIdx.x];
        sB[32 + threadIdx.x] = mb2[threadIdx.x];
        sB[64 + threadIdx.x] = ub1[threadIdx.x];
        sB[96 + threadIdx.x] = ub2[threadIdx.x];
    }
    __syncthreads();

    const int lane = threadIdx.x & 63;
    const int c    = lane & 31;
    const int half = lane >> 5;

    // per-lane private W1a column (src half, k=0..31) + W1c column (ef, k=0..3)
    float w1a[32], w1c[4];
    #pragma unroll
    for (int k = 0; k < 32; k++) w1a[k] = mw1[k * 32 + c];
    #pragma unroll
    for (int k = 0; k < 4; k++)  w1c[k] = mw1[(64 + k) * 32 + c];

    int wave   = (int)((blockIdx.x * 256 + threadIdx.x) >> 6);
    int nwaves = gridDim.x * 4;

    for (int n = wave; n < n_nodes; n += nwaves) {
        float hn = h_in[(size_t)n * 32 + c];   // own column of h[n]

        // base = mb1 + h[n] @ W1b   (broadcast h[n][k] via shfl)
        float base = sB[c];
        #pragma unroll
        for (int k = 0; k < 32; k++)
            base = fmaf(__shfl(hn, k, 32), sW1b[k * 32 + c], base);

        int s0 = row_start[n];
        int s1 = row_start[n + 1];
        float rsum = 0.0f;

        for (int s = s0 + half; s < s1; s += 2) {
            int2 sl = slots[s];                 // uniform per half-wave
            const float4* hs = (const float4*)(h_in + (size_t)sl.x * 32);
            float xs[32];
            #pragma unroll
            for (int q = 0; q < 8; q++) {       // wave-uniform row load
                float4 v = hs[q];
                xs[4 * q]     = v.x; xs[4 * q + 1] = v.y;
                xs[4 * q + 2] = v.z; xs[4 * q + 3] = v.w;
            }
            float4 ev = ef[sl.y];               // uniform per half-wave

            float acc = base;
            #pragma unroll
            for (int k = 0; k < 32; k++) acc = fmaf(xs[k], w1a[k], acc);
            acc = fmaf(ev.x, w1c[0], acc);
            acc = fmaf(ev.y, w1c[1], acc);
            acc = fmaf(ev.z, w1c[2], acc);
            acc = fmaf(ev.w, w1c[3], acc);
            rsum += fmaxf(acc, 0.0f);
        }
        // combine the two halves' partial sums (all 64 lanes active here)
        rsum += __shfl_xor(rsum, 32, 64);

        // agg = deg*mb2 + rsum @ W2
        float deg = (float)(s1 - s0);
        float agg = deg * sB[32 + c];
        #pragma unroll
        for (int k = 0; k < 32; k++)
            agg = fmaf(__shfl(rsum, k, 32), sW2[k * 32 + c], agg);

        // update MLP
        float a2 = sB[64 + c];
        #pragma unroll
        for (int k = 0; k < 32; k++)
            a2 = fmaf(__shfl(hn, k, 32), sU1[k * 32 + c], a2);
        #pragma unroll
        for (int k = 0; k < 32; k++)
            a2 = fmaf(__shfl(agg, k, 32), sU1[(32 + k) * 32 + c], a2);
        float t = fmaxf(a2, 0.0f);
        float o = sB[96 + c];
        #pragma unroll
        for (int k = 0; k < 32; k++)
            o = fmaf(__shfl(t, k, 32), sU2[k * 32 + c], o);

        if (lane < 32) h_out[(size_t)n * 32 + c] = hn + o;
    }
}

// -------- R14 fallback kernels (atomic path), used only if ws too small -----

__global__ void __launch_bounds__(256)
k_message(const float* __restrict__ h, const int2* __restrict__ edges,
          const float4* __restrict__ ef,
          const float* __restrict__ w1g, const float* __restrict__ b1g,
          const float* __restrict__ w2g, const float* __restrict__ b2g,
          float* __restrict__ agg, int n_edges)
{
    __shared__ float sw1[68 * 32];
    __shared__ float sw2[32 * 32];
    __shared__ float sb1[32];
    __shared__ float sb2[32];
    for (int i = threadIdx.x; i < 68 * 32; i += 256) sw1[i] = w1g[i];
    for (int i = threadIdx.x; i < 32 * 32; i += 256) sw2[i] = w2g[i];
    if (threadIdx.x < 32) {
        sb1[threadIdx.x] = b1g[threadIdx.x];
        sb2[threadIdx.x] = b2g[threadIdx.x];
    }
    __syncthreads();
    int e = blockIdx.x * 256 + threadIdx.x;
    if (e >= n_edges) return;

    int2 ed = edges[e];
    const float4* hs = (const float4*)(h + (size_t)ed.x * 32);
    const float4* hd = (const float4*)(h + (size_t)ed.y * 32);

    float acc[32];
    #pragma unroll
    for (int j = 0; j < 32; j++) acc[j] = sb1[j];
    #pragma unroll 2
    for (int cc = 0; cc < 8; cc++) {
        float4 xv = hs[cc];
        float xsv[4] = {xv.x, xv.y, xv.z, xv.w};
        #pragma unroll
        for (int kk = 0; kk < 4; kk++) {
            float xk = xsv[kk];
            const float* wr = &sw1[(cc * 4 + kk) * 32];
            #pragma unroll
            for (int j = 0; j < 32; j++) acc[j] = fmaf(xk, wr[j], acc[j]);
        }
    }
    #pragma unroll 2
    for (int cc = 0; cc < 8; cc++) {
        float4 xv = hd[cc];
        float xsv[4] = {xv.x, xv.y, xv.z, xv.w};
        #pragma unroll
        for (int kk = 0; kk < 4; kk++) {
            float xk = xsv[kk];
            const float* wr = &sw1[(32 + cc * 4 + kk) * 32];
            #pragma unroll
            for (int j = 0; j < 32; j++) acc[j] = fmaf(xk, wr[j], acc[j]);
        }
    }
    {
        float4 evv = ef[e];
        float ex[4] = {evv.x, evv.y, evv.z, evv.w};
        #pragma unroll
        for (int kk = 0; kk < 4; kk++) {
            float xk = ex[kk];
            const float* wr = &sw1[(64 + kk) * 32];
            #pragma unroll
            for (int j = 0; j < 32; j++) acc[j] = fmaf(xk, wr[j], acc[j]);
        }
    }
    #pragma unroll
    for (int j = 0; j < 32; j++) acc[j] = fmaxf(acc[j], 0.0f);

    float o[32];
    #pragma unroll
    for (int j = 0; j < 32; j++) o[j] = sb2[j];
    #pragma unroll 4
    for (int k = 0; k < 32; k++) {
        float hk = acc[k];
        const float* wr = &sw2[k * 32];
        #pragma unroll
        for (int j = 0; j < 32; j++) o[j] = fmaf(hk, wr[j], o[j]);
    }
    float* ap = agg + (size_t)ed.y * 32;
    #pragma unroll
    for (int j = 0; j < 32; j++) atomicAdd(ap + j, o[j]);
}

__global__ void __launch_bounds__(256)
k_update(float* h, const float* __restrict__ agg,
         const float* __restrict__ w1g, const float* __restrict__ b1g,
         const float* __restrict__ w2g, const float* __restrict__ b2g,
         int n_nodes)
{
    __shared__ float sw1[64 * 32];
    __shared__ float sw2[32 * 32];
    __shared__ float sb1[32];
    __shared__ float sb2[32];
    for (int i = threadIdx.x; i < 64 * 32; i += 256) sw1[i] = w1g[i];
    for (int i = threadIdx.x; i < 32 * 32; i += 256) sw2[i] = w2g[i];
    if (threadIdx.x < 32) {
        sb1[threadIdx.x] = b1g[threadIdx.x];
        sb2[threadIdx.x] = b2g[threadIdx.x];
    }
    __syncthreads();
    int n = blockIdx.x * 256 + threadIdx.x;
    if (n >= n_nodes) return;

    const float4* hp = (const float4*)(h + (size_t)n * 32);
    const float4* ap = (const float4*)(agg + (size_t)n * 32);

    float hv[32];
    float acc[32];
    #pragma unroll
    for (int j = 0; j < 32; j++) acc[j] = sb1[j];
    #pragma unroll 2
    for (int cc = 0; cc < 8; cc++) {
        float4 xv = hp[cc];
        hv[4 * cc] = xv.x; hv[4 * cc + 1] = xv.y; hv[4 * cc + 2] = xv.z; hv[4 * cc + 3] = xv.w;
        float xsv[4] = {xv.x, xv.y, xv.z, xv.w};
        #pragma unroll
        for (int kk = 0; kk < 4; kk++) {
            float xk = xsv[kk];
            const float* wr = &sw1[(cc * 4 + kk) * 32];
            #pragma unroll
            for (int j = 0; j < 32; j++) acc[j] = fmaf(xk, wr[j], acc[j]);
        }
    }
    #pragma unroll 2
    for (int cc = 0; cc < 8; cc++) {
        float4 xv = ap[cc];
        float xsv[4] = {xv.x, xv.y, xv.z, xv.w};
        #pragma unroll
        for (int kk = 0; kk < 4; kk++) {
            float xk = xsv[kk];
            const float* wr = &sw1[(32 + cc * 4 + kk) * 32];
            #pragma unroll
            for (int j = 0; j < 32; j++) acc[j] = fmaf(xk, wr[j], acc[j]);
        }
    }
    #pragma unroll
    for (int j = 0; j < 32; j++) acc[j] = fmaxf(acc[j], 0.0f);

    float o[32];
    #pragma unroll
    for (int j = 0; j < 32; j++) o[j] = sb2[j];
    #pragma unroll 4
    for (int k = 0; k < 32; k++) {
        float hk = acc[k];
        const float* wr = &sw2[k * 32];
        #pragma unroll
        for (int j = 0; j < 32; j++) o[j] = fmaf(hk, wr[j], o[j]);
    }
    float4* op = (float4*)(h + (size_t)n * 32);
    #pragma unroll
    for (int cc = 0; cc < 8; cc++)
        op[cc] = make_float4(hv[4 * cc] + o[4 * cc], hv[4 * cc + 1] + o[4 * cc + 1],
                             hv[4 * cc + 2] + o[4 * cc + 2], hv[4 * cc + 3] + o[4 * cc + 3]);
}

// head: out = (relu(h @ w1 + b1) @ w2 + b2)[:, 0]   (fp32 out)
__global__ void AtomGNN_56169582297457_kernel(const float* h, const float* w1g, const float* b1g, const float* w2g, const float* b2g, float* out, int n_nodes) {
    __shared__ float sw1[32 * 32];
    __shared__ float sb1[32];
    __shared__ float sw2[32];
    __shared__ float sb2;
    for (int i = threadIdx.x; i < 32 * 32; i += 256) sw1[i] = w1g[i];
    if (threadIdx.x < 32) {
        sb1[threadIdx.x] = b1g[threadIdx.x];
        sw2[threadIdx.x] = w2g[threadIdx.x];
    }
    if (threadIdx.x == 0) sb2 = b2g[0];
    __syncthreads();
    int n = blockIdx.x * 256 + threadIdx.x;
    if (n >= n_nodes) return;

    const float4* hp = (const float4*)(h + (size_t)n * 32);
    float x[32];
    #pragma unroll
    for (int cc = 0; cc < 8; cc++) {
        float4 xv = hp[cc];
        x[4 * cc] = xv.x; x[4 * cc + 1] = xv.y; x[4 * cc + 2] = xv.z; x[4 * cc + 3] = xv.w;
    }
    float acc[32];
    #pragma unroll
    for (int j = 0; j < 32; j++) acc[j] = sb1[j];
    #pragma unroll 4
    for (int k = 0; k < 32; k++) {
        float xk = x[k];
        const float* wr = &sw1[k * 32];
        #pragma unroll
        for (int j = 0; j < 32; j++) acc[j] = fmaf(xk, wr[j], acc[j]);
    }
    float val = sb2;
    #pragma unroll
    for (int k = 0; k < 32; k++) val = fmaf(fmaxf(acc[k], 0.0f), sw2[k], val);
    out[n] = val;
}

extern "C" void kernel_launch(void* const* d_in, const int* in_sizes, int n_in,
                              void* d_out, int out_size, void* d_ws, size_t ws_size,
                              hipStream_t stream) {
    const float* nf      = (const float*)d_in[0];
    const int2*  edges   = (const int2*)d_in[1];
    const float4* ef     = (const float4*)d_in[2];
    const float* enc_w1  = (const float*)d_in[3];
    const float* enc_b1  = (const float*)d_in[4];
    const float* enc_w2  = (const float*)d_in[5];
    const float* enc_b2  = (const float*)d_in[6];
    const float* msg_w1  = (const float*)d_in[7];
    const float* msg_b1  = (const float*)d_in[8];
    const float* msg_w2  = (const float*)d_in[9];
    const float* msg_b2  = (const float*)d_in[10];
    const float* upd_w1  = (const float*)d_in[11];
    const float* upd_b1  = (const float*)d_in[12];
    const float* upd_w2  = (const float*)d_in[13];
    const float* upd_b2  = (const float*)d_in[14];
    const float* head_w1 = (const float*)d_in[15];
    const float* head_b1 = (const float*)d_in[16];
    const float* head_w2 = (const float*)d_in[17];
    const float* head_b2 = (const float*)d_in[18];

    int n_nodes = (out_size > 0) ? out_size : NN_REF;
    int n_edges = (in_sizes && n_in > 2 && in_sizes[2] > 0) ? in_sizes[2] / 4 : NE_REF;

    int nb_nodes = (n_nodes + 255) / 256;
    int nb_edges = (n_edges + 255) / 256;

    // CSR workspace layout:
    //   h0[n*32] f32 | h1[n*32] f32 | row_start[n+1] i32 | cursor[n] i32 |
    //   bsum[nb] i32 | pad | slots[E] int2
    float* h0 = (float*)d_ws;
    float* h1 = h0 + (size_t)n_nodes * 32;
    int* row_start = (int*)(h1 + (size_t)n_nodes * 32);
    int* cursor = row_start + (n_nodes + 1);
    int* bsum = cursor + n_nodes;
    uintptr_t slots_addr = ((uintptr_t)(bsum + nb_nodes) + 15) & ~(uintptr_t)15;
    int2* slots = (int2*)slots_addr;
    size_t required = (slots_addr - (uintptr_t)d_ws) + (size_t)n_edges * sizeof(int2);

    bool csr_ok = (nb_nodes <= 1024) &&
                  (ws_size == 0 || ws_size >= required);

    if (csr_ok) {
        k_encode<<<nb_nodes, 256, 0, stream>>>(nf, enc_w1, enc_b1, enc_w2, enc_b2, h0, n_nodes);

        // build dst-CSR once (edges are identical across rounds)
        k_zero<<<256, 256, 0, stream>>>((float*)cursor, n_nodes);      // cursor as cnt
        k_hist<<<nb_edges, 256, 0, stream>>>(edges, cursor, n_edges);
        k_scan_block<<<nb_nodes, 256, 0, stream>>>(cursor, row_start, bsum, n_nodes);
        k_scan_bsum<<<1, 1024, 0, stream>>>(bsum, nb_nodes, row_start, n_nodes, n_edges);
        k_scan_add<<<nb_nodes, 256, 0, stream>>>(row_start, cursor, bsum, n_nodes);
        k_fill<<<nb_edges, 256, 0, stream>>>(edges, cursor, slots, n_edges);

        // ping-pong rounds: h0 -> h1 -> h0, wave-per-node fused kernel
        int nb_round = 2048;
        for (int r = 0; r < 2; r++) {
            const float* hin = (r == 0) ? h0 : h1;
            float* hout      = (r == 0) ? h1 : h0;
            k_round_wave<<<nb_round, 256, 0, stream>>>(
                hin, hout, row_start, slots, ef,
                msg_w1 + (size_t)r * 68 * 32, msg_b1 + (size_t)r * 32,
                msg_w2 + (size_t)r * 32 * 32, msg_b2 + (size_t)r * 32,
                upd_w1 + (size_t)r * 64 * 32, upd_b1 + (size_t)r * 32,
                upd_w2 + (size_t)r * 32 * 32, upd_b2 + (size_t)r * 32,
                n_nodes);
        }

        AtomGNN_56169582297457_kernel<<<nb_nodes, 256, 0, stream>>>(
            h0, head_w1, head_b1, head_w2, head_b2, (float*)d_out, n_nodes);
    } else {
        // R14 fallback: atomic scatter path (proven correct, slow)
        float* h   = (float*)d_ws;
        float* agg = h + (size_t)n_nodes * 32;

        k_encode<<<nb_nodes, 256, 0, stream>>>(nf, enc_w1, enc_b1, enc_w2, enc_b2, h, n_nodes);
        for (int r = 0; r < 2; r++) {
            k_zero<<<1024, 256, 0, stream>>>(agg, n_nodes * 32);
            k_message<<<nb_edges, 256, 0, stream>>>(
                h, edges, ef,
                msg_w1 + (size_t)r * 68 * 32, msg_b1 + (size_t)r * 32,
                msg_w2 + (size_t)r * 32 * 32, msg_b2 + (size_t)r * 32,
                agg, n_edges);
            k_update<<<nb_nodes, 256, 0, stream>>>(
                h, agg,
                upd_w1 + (size_t)r * 64 * 32, upd_b1 + (size_t)r * 32,
                upd_w2 + (size_t)r * 32 * 32, upd_b2 + (size_t)r * 32,
                n_nodes);
        }
        AtomGNN_56169582297457_kernel<<<nb_nodes, 256, 0, stream>>>(
            h, head_w1, head_b1, head_w2, head_b2, (float*)d_out, n_nodes);
    }
}